// Round 14
// baseline (6532.466 us; speedup 1.0000x reference)
//
#include <hip/hip_runtime.h>
#include <hip/hip_bf16.h>
#include <stdint.h>

#define BB 64
#define TT 512
#define DD 512
#define UU 1024
#define G4 4096
#define RETRY_CAP 16384

typedef __bf16 bf16x8 __attribute__((ext_vector_type(8)));
typedef float f32x4 __attribute__((ext_vector_type(4)));
typedef unsigned short u16x8 __attribute__((ext_vector_type(8)));
typedef int i32x4 __attribute__((ext_vector_type(4)));
typedef unsigned int u32;

__device__ __forceinline__ unsigned short f2bf(float f) {
  unsigned u = __builtin_bit_cast(unsigned, f);
  return (unsigned short)((u + 0x7FFFu + ((u >> 16) & 1u)) >> 16);  // RTN-even
}

// ---- x f32 -> bf16, same [B][T][D] layout, 8 elems/thread ----
__global__ void cvt_x_kernel(const float* __restrict__ x, unsigned short* __restrict__ xb, int n8) {
  int i = blockIdx.x * blockDim.x + threadIdx.x;
  if (i >= n8) return;
  const float4* p = reinterpret_cast<const float4*>(x) + (size_t)i * 2;
  float4 a = p[0], b = p[1];
  u16x8 o;
  o[0] = f2bf(a.x); o[1] = f2bf(a.y); o[2] = f2bf(a.z); o[3] = f2bf(a.w);
  o[4] = f2bf(b.x); o[5] = f2bf(b.y); o[6] = f2bf(b.z); o[7] = f2bf(b.w);
  reinterpret_cast<u16x8*>(xb)[i] = o;
}

// zero hbuf with write-through so readers see 0 tags (R2/R7-proven access type)
__global__ void zero_kernel(u32* __restrict__ p, int nwords) {
  for (int i = blockIdx.x * blockDim.x + threadIdx.x; i < nwords; i += gridDim.x * blockDim.x) {
    u32 z = 0u;
    const u32* q = p + i;
    asm volatile("global_store_dword %0, %1, off sc0 sc1" :: "v"(q), "v"(z) : "memory");
  }
}

// ---- persistent LSTM recurrence, flag-free self-validating h exchange ----
// R7 champion chassis + ONE change: `nt` (non-temporal / no-allocate) on all
// h transport. Theory: sc0 sc1 loads ALLOCATE in the local XCD L2, so retry
// loads hit a STALE L2 line until eviction (~12 retries ~= line lifetime) --
// that staleness window was the 7.7us/step. nt bypasses allocation so every
// retry reads the IC coherence point directly.
// 128 WGs x 512 thr (8 waves). bgrp=bid>>6 owns batch rows [bgrp*32,+32);
// m=bid&63 owns u [m*16,+16). Wave w k-split: x [w*64,+64), h [w*128,+128).
// h stored as u32 (bf16<<16 | step_tag): per-dword atomic self-validation,
// NO flags, NO store drain; consumer speculates + validates + retries.
__launch_bounds__(512, 1)
__global__ void lstm_persist(const float* __restrict__ W, const float* __restrict__ R,
                             const float* __restrict__ bias,
                             const unsigned short* __restrict__ xb,
                             u32* __restrict__ hbuf,   // [2 bgrp][2 buf][32][1024] u32
                             float* __restrict__ out) {
  __shared__ float zone[2 * 8 * 4 * 4 * 64];  // [rb][src][g][c][lane] f32, 64 KB

  const int bid = blockIdx.x;
  const int bgrp = bid >> 6;
  const int m = bid & 63;
  const int tid = threadIdx.x;
  const int w = tid >> 6;           // 0..7
  const int lane = tid & 63, l15 = lane & 15, lk = lane >> 4;
  const int rb = w & 1, rsel = w >> 1;  // gate ownership: row rb*16+lk*4+rsel
  const int u0 = m * 16;

  // ---- persistent weight fragments. B-frag: B[k0 + lk*8 + j][gcol] ----
  bf16x8 Wf[2][4];   // x: s=0..1, k0 = w*64 + s*32
  bf16x8 Rf[4][4];   // h: s=0..3, k0 = w*128 + s*32
  #pragma unroll
  for (int g = 0; g < 4; ++g) {
    const int gcol = g * 1024 + u0 + l15;
    #pragma unroll
    for (int s = 0; s < 2; ++s) {
      const int k0 = w * 64 + s * 32 + lk * 8;
      u16x8 tmp;
      #pragma unroll
      for (int j = 0; j < 8; ++j) tmp[j] = f2bf(W[(size_t)(k0 + j) * G4 + gcol]);
      Wf[s][g] = __builtin_bit_cast(bf16x8, tmp);
    }
    #pragma unroll
    for (int s = 0; s < 4; ++s) {
      const int k0 = w * 128 + s * 32 + lk * 8;
      u16x8 tmp;
      #pragma unroll
      for (int j = 0; j < 8; ++j) tmp[j] = f2bf(R[(size_t)(k0 + j) * G4 + gcol]);
      Rf[s][g] = __builtin_bit_cast(bf16x8, tmp);
    }
  }
  float bv[4];
  #pragma unroll
  for (int g = 0; g < 4; ++g) bv[g] = bias[g * 1024 + u0 + l15];

  float cst = 0.f;  // cell state for (row rb*16+lk*4+rsel, col u0+l15)

  // ---- pointers ----
  const unsigned short* xr0 = xb + (size_t)(bgrp * 32 + 0 + l15) * (TT * DD) + w * 64 + lk * 8;
  const unsigned short* xr1 = xb + (size_t)(bgrp * 32 + 16 + l15) * (TT * DD) + w * 64 + lk * 8;
  u32* hbg = hbuf + (size_t)bgrp * 2 * 32 * UU;
  // read bases per (parity, rl). A-frag lane (l15,lk) needs k = s*32 + lk*8 + [0..8)
  const u32* hrA0 = hbg + (size_t)(0 + l15) * UU + w * 128 + lk * 8;   // buf0, rl0
  const u32* hrA1 = hbg + (size_t)(16 + l15) * UU + w * 128 + lk * 8;  // buf0, rl1
  const u32* hrB0 = hrA0 + 32 * UU;                                    // buf1, rl0
  const u32* hrB1 = hrA1 + 32 * UU;                                    // buf1, rl1
  // store base per parity (this lane's single h word)
  u32* hsA = hbg + (size_t)(rb * 16 + lk * 4 + rsel) * UU + u0 + l15;  // buf0
  u32* hsB = hsA + 32 * UU;                                            // buf1

  // drain weight-load traffic before entering counted-vmcnt region
  asm volatile("s_waitcnt vmcnt(0)" ::: "memory");
  __builtin_amdgcn_sched_barrier(0);

  i32x4 H0[2][2], H1[2][2];  // [rl][q] for s-parity 0 / 1

#define HISSUE(Harr, S)                                                          \
  {                                                                              \
    const u32* p0 = b0 + (S) * 32;                                               \
    const u32* p1 = b1 + (S) * 32;                                               \
    asm volatile(                                                                \
        "global_load_dwordx4 %0, %4, off sc0 sc1 nt\n\t"                         \
        "global_load_dwordx4 %1, %4, off offset:16 sc0 sc1 nt\n\t"               \
        "global_load_dwordx4 %2, %5, off sc0 sc1 nt\n\t"                         \
        "global_load_dwordx4 %3, %5, off offset:16 sc0 sc1 nt"                   \
        : "=&v"(Harr[0][0]), "=&v"(Harr[0][1]), "=&v"(Harr[1][0]), "=&v"(Harr[1][1]) \
        : "v"(p0), "v"(p1)                                                       \
        : "memory");                                                             \
  }

#define VBAD(Harr, badv)                                                         \
  {                                                                              \
    badv = 0;                                                                    \
    _Pragma("unroll") for (int rl = 0; rl < 2; ++rl)                             \
        _Pragma("unroll") for (int q = 0; q < 2; ++q)                            \
            _Pragma("unroll") for (int d = 0; d < 4; ++d)                        \
                badv |= (Harr[rl][q][d] ^ t) & 0xFFFF;                           \
  }

#define VSTEP(Harr, S, VC)                                                       \
  {                                                                              \
    asm volatile("s_waitcnt vmcnt(" #VC ")" ::: "memory");                       \
    __builtin_amdgcn_sched_barrier(0);                                           \
    int bad;                                                                     \
    VBAD(Harr, bad);                                                             \
    int rtry = 0;                                                                \
    while (__any(bad != 0) && ++rtry < RETRY_CAP) {                              \
      HISSUE(Harr, S);                                                           \
      asm volatile("s_waitcnt vmcnt(0)" ::: "memory");                           \
      __builtin_amdgcn_sched_barrier(0);                                         \
      VBAD(Harr, bad);                                                           \
    }                                                                            \
    _Pragma("unroll") for (int rl = 0; rl < 2; ++rl) {                           \
      i32x4 fr;                                                                  \
      fr[0] = __builtin_amdgcn_perm(Harr[rl][0][1], Harr[rl][0][0], 0x07060302); \
      fr[1] = __builtin_amdgcn_perm(Harr[rl][0][3], Harr[rl][0][2], 0x07060302); \
      fr[2] = __builtin_amdgcn_perm(Harr[rl][1][1], Harr[rl][1][0], 0x07060302); \
      fr[3] = __builtin_amdgcn_perm(Harr[rl][1][3], Harr[rl][1][2], 0x07060302); \
      _Pragma("unroll") for (int g = 0; g < 4; ++g)                              \
          acc[rl][g] = __builtin_amdgcn_mfma_f32_16x16x32_bf16(                  \
              __builtin_bit_cast(bf16x8, fr), Rf[S][g], acc[rl][g], 0, 0, 0);    \
    }                                                                            \
  }

  #pragma unroll 1
  for (int t = 0; t < TT; ++t) {
    const int zb = t & 1;
    f32x4 acc[2][4];
    #pragma unroll
    for (int rl = 0; rl < 2; ++rl)
      #pragma unroll
      for (int g = 0; g < 4; ++g) acc[rl][g] = f32x4{0.f, 0.f, 0.f, 0.f};

    // issue x loads (cached)
    i32x4 Ax[2][2];  // [rl][s]
    asm volatile(
        "global_load_dwordx4 %0, %4, off\n\t"
        "global_load_dwordx4 %1, %4, off offset:64\n\t"
        "global_load_dwordx4 %2, %5, off\n\t"
        "global_load_dwordx4 %3, %5, off offset:64"
        : "=&v"(Ax[0][0]), "=&v"(Ax[0][1]), "=&v"(Ax[1][0]), "=&v"(Ax[1][1])
        : "v"(xr0), "v"(xr1));
    xr0 += DD; xr1 += DD;

    const u32* b0 = zb ? hrB0 : hrA0;
    const u32* b1 = zb ? hrB1 : hrA1;

    if (t > 0) {
      // speculative h loads for s=0,1; flight overlaps x-MFMA
      HISSUE(H0, 0);
      HISSUE(H1, 1);
      asm volatile("s_waitcnt vmcnt(8)" ::: "memory");  // x done (drains prev h-store too)
      __builtin_amdgcn_sched_barrier(0);
    } else {
      asm volatile("s_waitcnt vmcnt(0)" ::: "memory");
      __builtin_amdgcn_sched_barrier(0);
    }

    // x-part MFMA
    #pragma unroll
    for (int s = 0; s < 2; ++s)
      #pragma unroll
      for (int rl = 0; rl < 2; ++rl)
        #pragma unroll
        for (int g = 0; g < 4; ++g)
          acc[rl][g] = __builtin_amdgcn_mfma_f32_16x16x32_bf16(
              __builtin_bit_cast(bf16x8, Ax[rl][s]), Wf[s][g], acc[rl][g], 0, 0, 0);

    if (t > 0) {
      VSTEP(H0, 0, 4); HISSUE(H0, 2);
      VSTEP(H1, 1, 4); HISSUE(H1, 3);
      VSTEP(H0, 2, 4);
      VSTEP(H1, 3, 0);
    }

    // ---- k-split exchange: zone[rb][src][g][c][lane], conflict-free f32 ----
    __syncthreads();  // WAR: previous step's zone reads complete
    #pragma unroll
    for (int rl = 0; rl < 2; ++rl)
      #pragma unroll
      for (int g = 0; g < 4; ++g)
        #pragma unroll
        for (int c = 0; c < 4; ++c)
          zone[((((rl * 8 + w) * 4 + g) * 4 + c) << 6) + lane] = acc[rl][g][c];
    __syncthreads();

    // ---- gates: this wave owns (row rb*16+lk*4+rsel, u u0+l15) ----
    float z[4];
    #pragma unroll
    for (int g = 0; g < 4; ++g) {
      float s = bv[g];
      #pragma unroll
      for (int src = 0; src < 8; ++src)
        s += zone[((((rb * 8 + src) * 4 + g) * 4 + rsel) << 6) + lane];
      z[g] = s;
    }
    const float ig = 1.f / (1.f + __expf(-z[0]));
    const float fg = 1.f / (1.f + __expf(-z[1]));
    const float gg = 1.f - 2.f / (1.f + __expf(2.f * z[2]));  // tanh, inf-safe
    const float og = 1.f / (1.f + __expf(-z[3]));
    const float c = fg * cst + ig * gg;
    cst = c;
    const float h = og * (1.f - 2.f / (1.f + __expf(2.f * c)));

    if (t < TT - 1) {
      const u32 hw = ((u32)f2bf(h) << 16) | (u32)(t + 1);  // tag for consumers at t+1
      u32* hs = zb ? hsA : hsB;                            // store into buf (t+1)&1
      asm volatile("global_store_dword %0, %1, off sc0 sc1 nt" :: "v"(hs), "v"(hw) : "memory");
      // fire-and-forget: no drain, no flag
    } else {
      out[(size_t)(bgrp * 32 + rb * 16 + lk * 4 + rsel) * UU + u0 + l15] = h;
    }
  }
#undef HISSUE
#undef VBAD
#undef VSTEP
}

extern "C" void kernel_launch(void* const* d_in, const int* in_sizes, int n_in,
                              void* d_out, int out_size, void* d_ws, size_t ws_size,
                              hipStream_t stream) {
  const float* x = (const float*)d_in[0];
  const float* W = (const float*)d_in[1];
  const float* R = (const float*)d_in[2];
  const float* b = (const float*)d_in[3];
  float* out = (float*)d_out;

  char* ws = (char*)d_ws;
  unsigned short* xb = (unsigned short*)ws;                 // 32 MB
  const size_t XB_BYTES = (size_t)BB * TT * DD * 2;
  u32* hbuf = (u32*)(ws + XB_BYTES);                        // 2*2*32*1024*4 = 512 KB
  const int HB_WORDS = 2 * 2 * 32 * UU;

  hipLaunchKernelGGL(cvt_x_kernel, dim3((BB * TT * DD / 8 + 255) / 256), dim3(256), 0, stream,
                     x, xb, BB * TT * DD / 8);
  hipLaunchKernelGGL(zero_kernel, dim3(128), dim3(256), 0, stream, hbuf, HB_WORDS);
  hipLaunchKernelGGL(lstm_persist, dim3(128), dim3(512), 0, stream,
                     W, R, b, xb, hbuf, out);
}